// Round 10
// baseline (71.148 us; speedup 1.0000x reference)
//
#include <hip/hip_runtime.h>

#define NB 512
#define NT 256
#define NC 384
#define NH 64

typedef __bf16 bf16x8 __attribute__((ext_vector_type(8)));
typedef float f32x4 __attribute__((ext_vector_type(4)));
typedef float f32x16 __attribute__((ext_vector_type(16)));
typedef unsigned int u32;
typedef unsigned int u32x4 __attribute__((ext_vector_type(4)));
typedef unsigned short u16;

__device__ __forceinline__ u16 f2bf(float x) {
  u32 u = __builtin_bit_cast(u32, x);
  u32 r = (u + 0x7fffu + ((u >> 16) & 1u)) >> 16;  // RNE
  return (u16)r;
}
__device__ __forceinline__ u32 pkbf(float lo, float hi) {
  u32 r;
  asm("v_cvt_pk_bf16_f32 %0, %1, %2" : "=v"(r) : "v"(lo), "v"(hi));
  return r;
}
__device__ __forceinline__ void pl32swap(u32& a, u32& b) {
  asm volatile("v_permlane32_swap_b32 %0, %1" : "+v"(a), "+v"(b));
}

// ---------------- kernel 0: weights -> wb, pre-swizzled + K-permuted ---------
// wb is the exact 192x768B image later copied linearly into LDS:
//   wb[row][granule g][jj] = W[row, phys(g ^ (row&7), jj)]
// phys: within each K-chunk of 32, logical (lgj, jj) -> jj<4 ? lgj*4+jj
//       : 16 + lgj*4 + (jj-4)  (matches the contiguous x-load lane order)
__global__ __launch_bounds__(256) void wconv_k(const float* __restrict__ wk,
                                               const float* __restrict__ wq,
                                               const float* __restrict__ wv,
                                               u16* __restrict__ wb) {
  int i = blockIdx.x * 256 + threadIdx.x;
  if (i >= 192 * NC) return;
  int row = i / NC, c = i - row * NC;      // c = flat position within row image
  int g = c >> 3, jj = c & 7;              // granule 0..47, slot 0..7
  int lgr = g ^ (row & 7);                 // logical granule stored here
  int cl = lgr * 8 + jj;                   // logical column
  int chunk = cl >> 5, lgj = (cl >> 3) & 3, j = cl & 7;
  int phys = chunk * 32 + (j < 4 ? lgj * 4 + j : 16 + lgj * 4 + (j - 4));
  const float* s = (row < 64) ? wk : ((row < 128) ? wq : wv);
  wb[i] = f2bf(s[(row & 63) * NC + phys]);
}

// ---------------- fused kernel: QKV GEMM + attention -------------------------
// Phase 1: barrier-free GEMM; W LDS-resident (linear copy of pre-swizzled wb);
//   x loads 64-B contiguous per 4-lane group (pX = row bytes 0..63 of the
//   128-B K-chunk, pY = bytes 64..127); K-order permutation baked into wb.
// Phase 2: acc -> K/VT/Q in LDS; wave-pair f-split attention (unchanged).
__global__ __launch_bounds__(1024) void fused_k(const float* __restrict__ x,
                                                const u16* __restrict__ wb,
                                                float* __restrict__ out) {
  __shared__ __align__(16) char smem[147456];
  u16* Wl = (u16*)smem;
  const int tid = threadIdx.x;
  const int lane = tid & 63, w = tid >> 6;
  const int l15 = lane & 15, lg = lane >> 4;   // GEMM indexing
  const int l31 = lane & 31, gl = lane >> 5;   // attn indexing
  const size_t m0 = (size_t)blockIdx.x * 256;

  // ---- phase 1: GEMM ----
  const float* xp = x + (m0 + (size_t)(w * 16 + l15)) * NC + lg * 4;
  float4 pX[4], pY[4];
#pragma unroll
  for (int s = 0; s < 4; ++s) {
    pX[s] = *(const float4*)(xp + s * 32);        // row bytes 0..63 (4 lanes contig)
    pY[s] = *(const float4*)(xp + s * 32 + 16);   // row bytes 64..127
  }
  // W stage: pure linear copy (wb is pre-swizzled + K-permuted)
#pragma unroll
  for (int i = 0; i < 9; ++i) {
    int idx = tid + i * 1024;  // 0..9215 granules of 16 B
    *(uint4*)((char*)Wl + idx * 16) = *(const uint4*)((const char*)wb + idx * 16);
  }
  __syncthreads();

  f32x4 acc[12];
#pragma unroll
  for (int nt = 0; nt < 12; ++nt) {
    f32x4 z = {};
    acc[nt] = z;
  }
#pragma unroll
  for (int kk = 0; kk < 12; ++kk) {
    const int st = kk & 3;
    u32x4 av = {pkbf(pX[st].x, pX[st].y), pkbf(pX[st].z, pX[st].w),
                pkbf(pY[st].x, pY[st].y), pkbf(pY[st].z, pY[st].w)};
    bf16x8 afrag = __builtin_bit_cast(bf16x8, av);
    if (kk < 8) {
      pX[st] = *(const float4*)(xp + (kk + 4) * 32);
      pY[st] = *(const float4*)(xp + (kk + 4) * 32 + 16);
    }
#pragma unroll
    for (int nt = 0; nt < 12; ++nt) {
      int brow = nt * 16 + l15;
      bf16x8 b = *(const bf16x8*)((const char*)Wl + brow * 768 +
                                  (((kk * 4 + lg) ^ (brow & 7)) << 4));
      acc[nt] = __builtin_amdgcn_mfma_f32_16x16x32_bf16(afrag, b, acc[nt], 0, 0, 0);
    }
  }
  __syncthreads();  // Wl dead; reuse LDS

  // ---- phase 2a: acc -> Klds/Qlds/VT (attn layouts, swizzled) ----
  char* Kb = smem;
  char* Vb = smem + 32768;
  char* Qb = smem + 65536;
  float* mlb = (float*)(smem + 98304);    // m: [8][2][32]; l: +512 floats
  float* aob = (float*)(smem + 102400);   // [8][32][32] f32
#pragma unroll
  for (int nt = 0; nt < 12; ++nt) {
#pragma unroll
    for (int r = 0; r < 4; ++r) {
      int s = w * 16 + lg * 4 + r;        // row within batch (0..255)
      u16 v = f2bf(acc[nt][r]);
      if (nt < 4) {
        int h = nt * 16 + l15;
        *(u16*)(Kb + s * 128 + ((h * 2) ^ ((s & 7) << 4))) = v;
      } else if (nt < 8) {
        int h = (nt - 4) * 16 + l15;
        *(u16*)(Qb + s * 128 + ((h * 2) ^ ((s & 7) << 4))) = v;
      } else {
        int h = (nt - 8) * 16 + l15;
        *(u16*)(Vb + h * 512 + ((s * 2) ^ ((h & 7) << 4))) = v;
      }
    }
  }
  __syncthreads();

  // ---- phase 2b: attention ----
  const float cexp = 0.05103103630798287f * 1.4426950408889634f;  // C^-0.5*log2(e)
  const bool lo = (w < 8);
  const int qt = lo ? w : (15 - w);
  const int t0 = qt * 32;
  const int f1 = lo ? ((qt + 1 < 4) ? qt + 1 : 4) : (qt + 1);  // f in [f0,f1)
  const int f0 = lo ? 0 : 4;
  const int tq = t0 + l31;

  f32x16 sf[4];
#pragma unroll
  for (int fi = 0; fi < 4; ++fi) {
    int f = f0 + fi;
    if (f < f1) {
      f32x16 z = {};
      sf[fi] = z;
#pragma unroll
      for (int kk = 0; kk < 4; ++kk) {
        int arow = f * 32 + l31;
        bf16x8 a = *(const bf16x8*)(Kb + arow * 128 +
                                    ((kk * 32 + gl * 16) ^ ((arow & 7) << 4)));
        bf16x8 bq = *(const bf16x8*)(Qb + tq * 128 +
                                     ((kk * 32 + gl * 16) ^ ((tq & 7) << 4)));
        sf[fi] = __builtin_amdgcn_mfma_f32_32x32x16_bf16(a, bq, sf[fi], 0, 0, 0);
      }
    }
  }

  float pm = -INFINITY;
#pragma unroll
  for (int fi = 0; fi < 4; ++fi) {
    int f = f0 + fi;
    if (f < f1) {
      if (f < qt) {
#pragma unroll
        for (int r = 0; r < 16; ++r) pm = fmaxf(pm, sf[fi][r]);
      } else {
#pragma unroll
        for (int r = 0; r < 16; ++r) {
          int sloc = (r & 3) + 8 * (r >> 2) + 4 * gl;
          pm = fmaxf(pm, (sloc <= l31) ? sf[fi][r] : -INFINITY);
        }
      }
    }
  }
  pm = fmaxf(pm, __shfl_xor(pm, 32));
  if (gl == 0) mlb[(qt * 2 + (lo ? 0 : 1)) * 32 + l31] = pm;
  __syncthreads();
  float m = fmaxf(pm, mlb[(qt * 2 + (lo ? 1 : 0)) * 32 + l31]);

  float ls = 0.0f;
#pragma unroll
  for (int fi = 0; fi < 4; ++fi) {
    int f = f0 + fi;
    if (f < f1) {
#pragma unroll
      for (int r = 0; r < 16; ++r) {
        float e = exp2f((sf[fi][r] - m) * cexp);
        if (f == qt) {
          int sloc = (r & 3) + 8 * (r >> 2) + 4 * gl;
          e = (sloc <= l31) ? e : 0.0f;
        }
        sf[fi][r] = e;
        ls += e;
      }
    }
  }
  ls += __shfl_xor(ls, 32);
  if (gl == 0) mlb[512 + (qt * 2 + (lo ? 0 : 1)) * 32 + l31] = ls;
  __syncthreads();
  float lsum = ls + mlb[512 + (qt * 2 + (lo ? 1 : 0)) * 32 + l31];

  f32x16 ao0 = {}, ao1 = {};
#pragma unroll
  for (int fi = 0; fi < 4; ++fi) {
    int f = f0 + fi;
    if (f < f1) {
      u32 a0 = pkbf(sf[fi][0], sf[fi][1]);
      u32 a1 = pkbf(sf[fi][2], sf[fi][3]);
      u32 b0 = pkbf(sf[fi][4], sf[fi][5]);
      u32 b1 = pkbf(sf[fi][6], sf[fi][7]);
      pl32swap(a0, b0);
      pl32swap(a1, b1);
      u32x4 te = {a0, a1, b0, b1};
      bf16x8 bpe = __builtin_bit_cast(bf16x8, te);
      u32 c0 = pkbf(sf[fi][8], sf[fi][9]);
      u32 c1 = pkbf(sf[fi][10], sf[fi][11]);
      u32 d0 = pkbf(sf[fi][12], sf[fi][13]);
      u32 d1 = pkbf(sf[fi][14], sf[fi][15]);
      pl32swap(c0, d0);
      pl32swap(c1, d1);
      u32x4 to = {c0, c1, d0, d1};
      bf16x8 bpo = __builtin_bit_cast(bf16x8, to);

      int se = (f * 32 + gl * 8) * 2;
      int so = se + 32;
      bf16x8 av0e = *(const bf16x8*)(Vb + l31 * 512 + (se ^ ((l31 & 7) << 4)));
      bf16x8 av1e = *(const bf16x8*)(Vb + (32 + l31) * 512 + (se ^ ((l31 & 7) << 4)));
      ao0 = __builtin_amdgcn_mfma_f32_32x32x16_bf16(av0e, bpe, ao0, 0, 0, 0);
      ao1 = __builtin_amdgcn_mfma_f32_32x32x16_bf16(av1e, bpe, ao1, 0, 0, 0);
      bf16x8 av0o = *(const bf16x8*)(Vb + l31 * 512 + (so ^ ((l31 & 7) << 4)));
      bf16x8 av1o = *(const bf16x8*)(Vb + (32 + l31) * 512 + (so ^ ((l31 & 7) << 4)));
      ao0 = __builtin_amdgcn_mfma_f32_32x32x16_bf16(av0o, bpo, ao0, 0, 0, 0);
      ao1 = __builtin_amdgcn_mfma_f32_32x32x16_bf16(av1o, bpo, ao1, 0, 0, 0);
    }
  }

  if (!lo) {
#pragma unroll
    for (int r = 0; r < 16; ++r) {
      int hrow = (r & 3) + 8 * (r >> 2) + 4 * gl;
      aob[qt * 1024 + hrow * 32 + l31] = ao0[r];
    }
  }
  __syncthreads();
  if (lo) {
#pragma unroll
    for (int r = 0; r < 16; ++r) {
      int hrow = (r & 3) + 8 * (r >> 2) + 4 * gl;
      ao0[r] += aob[qt * 1024 + hrow * 32 + l31];
    }
  }
  __syncthreads();
  if (!lo) {
#pragma unroll
    for (int r = 0; r < 16; ++r) {
      int hrow = (r & 3) + 8 * (r >> 2) + 4 * gl;
      aob[qt * 1024 + hrow * 32 + l31] = ao1[r];
    }
  }
  __syncthreads();
  if (lo) {
    float rl = 1.0f / lsum;
    float* ob = out + (m0 + t0 + l31) * NH;
#pragma unroll
    for (int g = 0; g < 4; ++g) {
      float4 v0, v1;
#pragma unroll
      for (int j = 0; j < 4; ++j) {
        int r = 4 * g + j;
        int hrow = (r & 3) + 8 * (r >> 2) + 4 * gl;
        float a1c = ao1[r] + aob[qt * 1024 + hrow * 32 + l31];
        ((float*)&v0)[j] = ao0[r] * rl;
        ((float*)&v1)[j] = a1c * rl;
      }
      *(float4*)(ob + 8 * g + 4 * gl) = v0;
      *(float4*)(ob + 32 + 8 * g + 4 * gl) = v1;
    }
  }
}

// ---------------- launch -----------------------------------------------------
extern "C" void kernel_launch(void* const* d_in, const int* in_sizes, int n_in,
                              void* d_out, int out_size, void* d_ws, size_t ws_size,
                              hipStream_t stream) {
  const float* x = (const float*)d_in[0];
  const float* wk = (const float*)d_in[1];
  const float* wq = (const float*)d_in[2];
  const float* wv = (const float*)d_in[3];
  float* out = (float*)d_out;

  u16* wb = (u16*)d_ws;  // 147456 B

  wconv_k<<<288, 256, 0, stream>>>(wk, wq, wv, wb);
  fused_k<<<512, 1024, 0, stream>>>(x, wb, out);
}

// Round 11
// 67.213 us; speedup vs baseline: 1.0585x; 1.0585x over previous
//
#include <hip/hip_runtime.h>

#define NB 512
#define NT 256
#define NC 384
#define NH 64

typedef __bf16 bf16x8 __attribute__((ext_vector_type(8)));
typedef float f32x4 __attribute__((ext_vector_type(4)));
typedef float f32x16 __attribute__((ext_vector_type(16)));
typedef unsigned int u32;
typedef unsigned int u32x4 __attribute__((ext_vector_type(4)));
typedef unsigned short u16;

__device__ __forceinline__ u16 f2bf(float x) {
  u32 u = __builtin_bit_cast(u32, x);
  u32 r = (u + 0x7fffu + ((u >> 16) & 1u)) >> 16;  // RNE
  return (u16)r;
}
__device__ __forceinline__ u32 pkbf(float lo, float hi) {
  u32 r;
  asm("v_cvt_pk_bf16_f32 %0, %1, %2" : "=v"(r) : "v"(lo), "v"(hi));
  return r;
}
__device__ __forceinline__ void pl32swap(u32& a, u32& b) {
  asm volatile("v_permlane32_swap_b32 %0, %1" : "+v"(a), "+v"(b));
}

// ---------------- kernel 0: weights -> wb, pre-swizzled + K-permuted ---------
// wb[row][granule g][jj] = W[row, phys(g ^ (row&7), jj)]
// phys: within each K-chunk of 32, logical (lgj, jj) -> jj<4 ? lgj*4+jj
//       : 16 + lgj*4 + (jj-4)  (matches the contiguous x-load lane order)
__global__ __launch_bounds__(256) void wconv_k(const float* __restrict__ wk,
                                               const float* __restrict__ wq,
                                               const float* __restrict__ wv,
                                               u16* __restrict__ wb) {
  int i = blockIdx.x * 256 + threadIdx.x;
  if (i >= 192 * NC) return;
  int row = i / NC, c = i - row * NC;      // c = flat position within row image
  int g = c >> 3, jj = c & 7;              // granule 0..47, slot 0..7
  int lgr = g ^ (row & 7);                 // logical granule stored here
  int cl = lgr * 8 + jj;                   // logical column
  int chunk = cl >> 5, lgj = (cl >> 3) & 3, j = cl & 7;
  int phys = chunk * 32 + (j < 4 ? lgj * 4 + j : 16 + lgj * 4 + (j - 4));
  const float* s = (row < 64) ? wk : ((row < 128) ? wq : wv);
  wb[i] = f2bf(s[(row & 63) * NC + phys]);
}

// ---------------- fused kernel: QKV GEMM + attention -------------------------
// Phase 1: barrier-free GEMM; W LDS-resident (linear copy of pre-swizzled wb);
//   per-wave K-chunk ROTATION rot=(w+bid)%12 de-aliases HBM channel phases
//   (16-row x 1536-B-stride wave-loads otherwise all hit the same 256-B-slot
//   parity in near-lockstep across the grid).
// Phase 2: acc -> K/VT/Q in LDS; wave-pair f-split attention (unchanged).
__global__ __launch_bounds__(1024) void fused_k(const float* __restrict__ x,
                                                const u16* __restrict__ wb,
                                                float* __restrict__ out) {
  __shared__ __align__(16) char smem[147456];
  u16* Wl = (u16*)smem;
  const int tid = threadIdx.x;
  const int lane = tid & 63, w = tid >> 6;
  const int l15 = lane & 15, lg = lane >> 4;   // GEMM indexing
  const int l31 = lane & 31, gl = lane >> 5;   // attn indexing
  const int s7 = l15 & 7;
  const size_t m0 = (size_t)blockIdx.x * 256;

  // ---- phase 1: GEMM ----
  const float* xp = x + (m0 + (size_t)(w * 16 + l15)) * NC + lg * 4;
  const int rot = (w + (int)blockIdx.x) % 12;

  float4 pX[4], pY[4];
#pragma unroll
  for (int s = 0; s < 4; ++s) {
    int kc = rot + s; if (kc >= 12) kc -= 12;
    pX[s] = *(const float4*)(xp + kc * 32);        // row bytes 0..63 of chunk
    pY[s] = *(const float4*)(xp + kc * 32 + 16);   // row bytes 64..127
  }
  // W stage: pure linear copy (wb is pre-swizzled + K-permuted)
#pragma unroll
  for (int i = 0; i < 9; ++i) {
    int idx = tid + i * 1024;  // 0..9215 granules of 16 B
    *(uint4*)((char*)Wl + idx * 16) = *(const uint4*)((const char*)wb + idx * 16);
  }
  __syncthreads();

  f32x4 acc[12];
#pragma unroll
  for (int nt = 0; nt < 12; ++nt) {
    f32x4 z = {};
    acc[nt] = z;
  }
#pragma unroll
  for (int kk = 0; kk < 12; ++kk) {
    const int st = kk & 3;
    int kc = rot + kk; if (kc >= 12) kc -= 12;
    u32x4 av = {pkbf(pX[st].x, pX[st].y), pkbf(pX[st].z, pX[st].w),
                pkbf(pY[st].x, pY[st].y), pkbf(pY[st].z, pY[st].w)};
    bf16x8 afrag = __builtin_bit_cast(bf16x8, av);
    if (kk < 8) {
      int kc4 = rot + kk + 4; if (kc4 >= 12) kc4 -= 12;
      pX[st] = *(const float4*)(xp + kc4 * 32);
      pY[st] = *(const float4*)(xp + kc4 * 32 + 16);
    }
    const int xorp = ((kc * 4 + lg) ^ s7) << 4;
#pragma unroll
    for (int nt = 0; nt < 12; ++nt) {
      int brow = nt * 16 + l15;
      bf16x8 b = *(const bf16x8*)((const char*)Wl + brow * 768 + xorp);
      acc[nt] = __builtin_amdgcn_mfma_f32_16x16x32_bf16(afrag, b, acc[nt], 0, 0, 0);
    }
  }
  __syncthreads();  // Wl dead; reuse LDS

  // ---- phase 2a: acc -> Klds/Qlds/VT (attn layouts, swizzled) ----
  char* Kb = smem;
  char* Vb = smem + 32768;
  char* Qb = smem + 65536;
  float* mlb = (float*)(smem + 98304);    // m: [8][2][32]; l: +512 floats
  float* aob = (float*)(smem + 102400);   // [8][32][32] f32
#pragma unroll
  for (int nt = 0; nt < 12; ++nt) {
#pragma unroll
    for (int r = 0; r < 4; ++r) {
      int s = w * 16 + lg * 4 + r;        // row within batch (0..255)
      u16 v = f2bf(acc[nt][r]);
      if (nt < 4) {
        int h = nt * 16 + l15;
        *(u16*)(Kb + s * 128 + ((h * 2) ^ ((s & 7) << 4))) = v;
      } else if (nt < 8) {
        int h = (nt - 4) * 16 + l15;
        *(u16*)(Qb + s * 128 + ((h * 2) ^ ((s & 7) << 4))) = v;
      } else {
        int h = (nt - 8) * 16 + l15;
        *(u16*)(Vb + h * 512 + ((s * 2) ^ ((h & 7) << 4))) = v;
      }
    }
  }
  __syncthreads();

  // ---- phase 2b: attention ----
  const float cexp = 0.05103103630798287f * 1.4426950408889634f;  // C^-0.5*log2(e)
  const bool lo = (w < 8);
  const int qt = lo ? w : (15 - w);
  const int t0 = qt * 32;
  const int f1 = lo ? ((qt + 1 < 4) ? qt + 1 : 4) : (qt + 1);  // f in [f0,f1)
  const int f0 = lo ? 0 : 4;
  const int tq = t0 + l31;

  f32x16 sf[4];
#pragma unroll
  for (int fi = 0; fi < 4; ++fi) {
    int f = f0 + fi;
    if (f < f1) {
      f32x16 z = {};
      sf[fi] = z;
#pragma unroll
      for (int kk = 0; kk < 4; ++kk) {
        int arow = f * 32 + l31;
        bf16x8 a = *(const bf16x8*)(Kb + arow * 128 +
                                    ((kk * 32 + gl * 16) ^ ((arow & 7) << 4)));
        bf16x8 bq = *(const bf16x8*)(Qb + tq * 128 +
                                     ((kk * 32 + gl * 16) ^ ((tq & 7) << 4)));
        sf[fi] = __builtin_amdgcn_mfma_f32_32x32x16_bf16(a, bq, sf[fi], 0, 0, 0);
      }
    }
  }

  float pm = -INFINITY;
#pragma unroll
  for (int fi = 0; fi < 4; ++fi) {
    int f = f0 + fi;
    if (f < f1) {
      if (f < qt) {
#pragma unroll
        for (int r = 0; r < 16; ++r) pm = fmaxf(pm, sf[fi][r]);
      } else {
#pragma unroll
        for (int r = 0; r < 16; ++r) {
          int sloc = (r & 3) + 8 * (r >> 2) + 4 * gl;
          pm = fmaxf(pm, (sloc <= l31) ? sf[fi][r] : -INFINITY);
        }
      }
    }
  }
  pm = fmaxf(pm, __shfl_xor(pm, 32));
  if (gl == 0) mlb[(qt * 2 + (lo ? 0 : 1)) * 32 + l31] = pm;
  __syncthreads();
  float m = fmaxf(pm, mlb[(qt * 2 + (lo ? 1 : 0)) * 32 + l31]);

  float ls = 0.0f;
#pragma unroll
  for (int fi = 0; fi < 4; ++fi) {
    int f = f0 + fi;
    if (f < f1) {
#pragma unroll
      for (int r = 0; r < 16; ++r) {
        float e = exp2f((sf[fi][r] - m) * cexp);
        if (f == qt) {
          int sloc = (r & 3) + 8 * (r >> 2) + 4 * gl;
          e = (sloc <= l31) ? e : 0.0f;
        }
        sf[fi][r] = e;
        ls += e;
      }
    }
  }
  ls += __shfl_xor(ls, 32);
  if (gl == 0) mlb[512 + (qt * 2 + (lo ? 0 : 1)) * 32 + l31] = ls;
  __syncthreads();
  float lsum = ls + mlb[512 + (qt * 2 + (lo ? 1 : 0)) * 32 + l31];

  f32x16 ao0 = {}, ao1 = {};
#pragma unroll
  for (int fi = 0; fi < 4; ++fi) {
    int f = f0 + fi;
    if (f < f1) {
      u32 a0 = pkbf(sf[fi][0], sf[fi][1]);
      u32 a1 = pkbf(sf[fi][2], sf[fi][3]);
      u32 b0 = pkbf(sf[fi][4], sf[fi][5]);
      u32 b1 = pkbf(sf[fi][6], sf[fi][7]);
      pl32swap(a0, b0);
      pl32swap(a1, b1);
      u32x4 te = {a0, a1, b0, b1};
      bf16x8 bpe = __builtin_bit_cast(bf16x8, te);
      u32 c0 = pkbf(sf[fi][8], sf[fi][9]);
      u32 c1 = pkbf(sf[fi][10], sf[fi][11]);
      u32 d0 = pkbf(sf[fi][12], sf[fi][13]);
      u32 d1 = pkbf(sf[fi][14], sf[fi][15]);
      pl32swap(c0, d0);
      pl32swap(c1, d1);
      u32x4 to = {c0, c1, d0, d1};
      bf16x8 bpo = __builtin_bit_cast(bf16x8, to);

      int se = (f * 32 + gl * 8) * 2;
      int so = se + 32;
      bf16x8 av0e = *(const bf16x8*)(Vb + l31 * 512 + (se ^ ((l31 & 7) << 4)));
      bf16x8 av1e = *(const bf16x8*)(Vb + (32 + l31) * 512 + (se ^ ((l31 & 7) << 4)));
      ao0 = __builtin_amdgcn_mfma_f32_32x32x16_bf16(av0e, bpe, ao0, 0, 0, 0);
      ao1 = __builtin_amdgcn_mfma_f32_32x32x16_bf16(av1e, bpe, ao1, 0, 0, 0);
      bf16x8 av0o = *(const bf16x8*)(Vb + l31 * 512 + (so ^ ((l31 & 7) << 4)));
      bf16x8 av1o = *(const bf16x8*)(Vb + (32 + l31) * 512 + (so ^ ((l31 & 7) << 4)));
      ao0 = __builtin_amdgcn_mfma_f32_32x32x16_bf16(av0o, bpo, ao0, 0, 0, 0);
      ao1 = __builtin_amdgcn_mfma_f32_32x32x16_bf16(av1o, bpo, ao1, 0, 0, 0);
    }
  }

  if (!lo) {
#pragma unroll
    for (int r = 0; r < 16; ++r) {
      int hrow = (r & 3) + 8 * (r >> 2) + 4 * gl;
      aob[qt * 1024 + hrow * 32 + l31] = ao0[r];
    }
  }
  __syncthreads();
  if (lo) {
#pragma unroll
    for (int r = 0; r < 16; ++r) {
      int hrow = (r & 3) + 8 * (r >> 2) + 4 * gl;
      ao0[r] += aob[qt * 1024 + hrow * 32 + l31];
    }
  }
  __syncthreads();
  if (!lo) {
#pragma unroll
    for (int r = 0; r < 16; ++r) {
      int hrow = (r & 3) + 8 * (r >> 2) + 4 * gl;
      aob[qt * 1024 + hrow * 32 + l31] = ao1[r];
    }
  }
  __syncthreads();
  if (lo) {
    float rl = 1.0f / lsum;
    float* ob = out + (m0 + t0 + l31) * NH;
#pragma unroll
    for (int g = 0; g < 4; ++g) {
      float4 v0, v1;
#pragma unroll
      for (int j = 0; j < 4; ++j) {
        int r = 4 * g + j;
        int hrow = (r & 3) + 8 * (r >> 2) + 4 * gl;
        float a1c = ao1[r] + aob[qt * 1024 + hrow * 32 + l31];
        ((float*)&v0)[j] = ao0[r] * rl;
        ((float*)&v1)[j] = a1c * rl;
      }
      *(float4*)(ob + 8 * g + 4 * gl) = v0;
      *(float4*)(ob + 32 + 8 * g + 4 * gl) = v1;
    }
  }
}

// ---------------- launch -----------------------------------------------------
extern "C" void kernel_launch(void* const* d_in, const int* in_sizes, int n_in,
                              void* d_out, int out_size, void* d_ws, size_t ws_size,
                              hipStream_t stream) {
  const float* x = (const float*)d_in[0];
  const float* wk = (const float*)d_in[1];
  const float* wq = (const float*)d_in[2];
  const float* wv = (const float*)d_in[3];
  float* out = (float*)d_out;

  u16* wb = (u16*)d_ws;  // 147456 B

  wconv_k<<<288, 256, 0, stream>>>(wk, wq, wv, wb);
  fused_k<<<512, 1024, 0, stream>>>(x, wb, out);
}